// Round 1
// baseline (211.732 us; speedup 1.0000x reference)
//
#include <hip/hip_runtime.h>

#define W 1024
#define H 1024
#define NIMG 64
#define NBINS 256
#define NPIX (W * H)                     // per image
#define NTOT ((long long)NIMG * NPIX)    // 67108864
#define NSLOT 256                        // accumulator slots

// workspace layout (bytes):
//   [0,            65536)  : per-image histograms, 64*256 u32
//   [65536,       131072)  : per-image LUTs (already /255), 64*256 f32
//   [131072,      135168)  : accumulator slots, NSLOT * 2 doubles
#define WS_HIST 0
#define WS_LUT  65536
#define WS_ACC  131072
#define WS_TOTAL (131072 + NSLOT * 2 * 8)

__global__ __launch_bounds__(256) void hist_kernel(const float* __restrict__ img,
                                                   unsigned int* __restrict__ ghist) {
    __shared__ unsigned int lh[NBINS];
    const int b = blockIdx.y;
    for (int i = threadIdx.x; i < NBINS; i += 256) lh[i] = 0u;
    __syncthreads();
    const float4* p = (const float4*)(img + (size_t)b * NPIX);
    const int nvec = NPIX / 4;
    const int stride = gridDim.x * 256;
    for (int i = blockIdx.x * 256 + threadIdx.x; i < nvec; i += stride) {
        float4 v = p[i];
        atomicAdd(&lh[min(max((int)v.x, 0), 255)], 1u);
        atomicAdd(&lh[min(max((int)v.y, 0), 255)], 1u);
        atomicAdd(&lh[min(max((int)v.z, 0), 255)], 1u);
        atomicAdd(&lh[min(max((int)v.w, 0), 255)], 1u);
    }
    __syncthreads();
    for (int i = threadIdx.x; i < NBINS; i += 256) {
        unsigned int c = lh[i];
        if (c) atomicAdd(&ghist[b * NBINS + i], c);
    }
}

__global__ __launch_bounds__(256) void lut_kernel(const unsigned int* __restrict__ ghist,
                                                  float* __restrict__ lut) {
    __shared__ float cdf[NBINS];
    __shared__ float s_cdfmin;
    const int b = blockIdx.x;
    const int t = threadIdx.x;
    cdf[t] = (float)ghist[b * NBINS + t];
    __syncthreads();
    // Hillis-Steele inclusive scan (float, exact: integer counts < 2^24)
    for (int off = 1; off < NBINS; off <<= 1) {
        float add = (t >= off) ? cdf[t - off] : 0.0f;
        __syncthreads();
        cdf[t] += add;
        __syncthreads();
    }
    if (t == 0) {
        float m = 0.0f;
        for (int i = 0; i < NBINS; ++i) {
            if (cdf[i] > 0.0f) { m = cdf[i]; break; }
        }
        s_cdfmin = m;
    }
    __syncthreads();
    const float total = (float)NPIX;
    const float scale = 255.0f / fmaxf(total - s_cdfmin, 1.0f);
    float l = fminf(fmaxf(rintf((cdf[t] - s_cdfmin) * scale), 0.0f), 255.0f);
    lut[b * NBINS + t] = l / 255.0f;
}

__global__ __launch_bounds__(256) void lap_kernel(const float* __restrict__ img,
                                                  const float* __restrict__ lut,
                                                  double* __restrict__ acc) {
    __shared__ float slut[NBINS];
    const int y = blockIdx.x;
    const int b = blockIdx.y;
    const int t = threadIdx.x;
    slut[t] = lut[b * NBINS + t];
    __syncthreads();

    const float* base = img + (size_t)b * NPIX + (size_t)y * W;
    const int x0 = t * 4;

    float4 c4 = *(const float4*)(base + x0);
    float4 u4 = make_float4(0.f, 0.f, 0.f, 0.f);
    float4 d4 = make_float4(0.f, 0.f, 0.f, 0.f);
    if (y > 0)     u4 = *(const float4*)(base - W + x0);
    if (y < H - 1) d4 = *(const float4*)(base + W + x0);
    float lv = (x0 > 0)     ? base[x0 - 1] : 0.0f;
    float rv = (x0 + 4 < W) ? base[x0 + 4] : 0.0f;

    // eq values; out-of-bounds taps are ZERO (conv zero-padding applies to eq)
    float ec0 = slut[min(max((int)c4.x, 0), 255)];
    float ec1 = slut[min(max((int)c4.y, 0), 255)];
    float ec2 = slut[min(max((int)c4.z, 0), 255)];
    float ec3 = slut[min(max((int)c4.w, 0), 255)];
    float eu0 = 0.f, eu1 = 0.f, eu2 = 0.f, eu3 = 0.f;
    float ed0 = 0.f, ed1 = 0.f, ed2 = 0.f, ed3 = 0.f;
    if (y > 0) {
        eu0 = slut[min(max((int)u4.x, 0), 255)];
        eu1 = slut[min(max((int)u4.y, 0), 255)];
        eu2 = slut[min(max((int)u4.z, 0), 255)];
        eu3 = slut[min(max((int)u4.w, 0), 255)];
    }
    if (y < H - 1) {
        ed0 = slut[min(max((int)d4.x, 0), 255)];
        ed1 = slut[min(max((int)d4.y, 0), 255)];
        ed2 = slut[min(max((int)d4.z, 0), 255)];
        ed3 = slut[min(max((int)d4.w, 0), 255)];
    }
    float el = (x0 > 0)     ? slut[min(max((int)lv, 0), 255)] : 0.0f;
    float er = (x0 + 4 < W) ? slut[min(max((int)rv, 0), 255)] : 0.0f;

    float lap0 = eu0 + ed0 + el  + ec1 - 4.0f * ec0;
    float lap1 = eu1 + ed1 + ec0 + ec2 - 4.0f * ec1;
    float lap2 = eu2 + ed2 + ec1 + ec3 - 4.0f * ec2;
    float lap3 = eu3 + ed3 + ec2 + er  - 4.0f * ec3;

    double s = (double)lap0 + (double)lap1 + (double)lap2 + (double)lap3;
    double q = (double)lap0 * lap0 + (double)lap1 * lap1 +
               (double)lap2 * lap2 + (double)lap3 * lap3;

    // wave-64 butterfly then cross-wave via LDS
    for (int off = 32; off > 0; off >>= 1) {
        s += __shfl_down(s, off, 64);
        q += __shfl_down(q, off, 64);
    }
    __shared__ double ssum[4];
    __shared__ double ssq[4];
    const int wave = t >> 6;
    const int lane = t & 63;
    if (lane == 0) { ssum[wave] = s; ssq[wave] = q; }
    __syncthreads();
    if (t == 0) {
        double S = ssum[0] + ssum[1] + ssum[2] + ssum[3];
        double Q = ssq[0] + ssq[1] + ssq[2] + ssq[3];
        const int slot = (blockIdx.x + blockIdx.y * gridDim.x) & (NSLOT - 1);
        atomicAdd(&acc[2 * slot], S);
        atomicAdd(&acc[2 * slot + 1], Q);
    }
}

__global__ __launch_bounds__(256) void finalize_kernel(const double* __restrict__ acc,
                                                       float* __restrict__ out) {
    const int t = threadIdx.x;
    double s = acc[2 * t];
    double q = acc[2 * t + 1];
    for (int off = 32; off > 0; off >>= 1) {
        s += __shfl_down(s, off, 64);
        q += __shfl_down(q, off, 64);
    }
    __shared__ double ssum[4];
    __shared__ double ssq[4];
    const int wave = t >> 6;
    const int lane = t & 63;
    if (lane == 0) { ssum[wave] = s; ssq[wave] = q; }
    __syncthreads();
    if (t == 0) {
        double S = ssum[0] + ssum[1] + ssum[2] + ssum[3];
        double Q = ssq[0] + ssq[1] + ssq[2] + ssq[3];
        const double N = (double)NTOT;
        double var = (Q - S * S / N) / (N - 1.0);
        out[0] = (float)var;
    }
}

extern "C" void kernel_launch(void* const* d_in, const int* in_sizes, int n_in,
                              void* d_out, int out_size, void* d_ws, size_t ws_size,
                              hipStream_t stream) {
    const float* img = (const float*)d_in[0];
    float* out = (float*)d_out;

    unsigned int* ghist = (unsigned int*)((char*)d_ws + WS_HIST);
    float* lut          = (float*)((char*)d_ws + WS_LUT);
    double* acc         = (double*)((char*)d_ws + WS_ACC);

    hipMemsetAsync(d_ws, 0, WS_TOTAL, stream);

    dim3 hgrid(64, NIMG);
    hist_kernel<<<hgrid, 256, 0, stream>>>(img, ghist);

    lut_kernel<<<NIMG, NBINS, 0, stream>>>(ghist, lut);

    dim3 lgrid(H, NIMG);
    lap_kernel<<<lgrid, 256, 0, stream>>>(img, lut, acc);

    finalize_kernel<<<1, 256, 0, stream>>>(acc, out);
}

// Round 2
// 136.906 us; speedup vs baseline: 1.5466x; 1.5466x over previous
//
#include <hip/hip_runtime.h>

#define W 1024
#define H 1024
#define NIMG 64
#define NBINS 256
#define NPIX (W * H)                       // per image
#define NTOT ((long long)NIMG * NPIX)      // 67108864
#define NSLOT 256
#define RSTRIP 16                          // rows per lap block

typedef float f32x4 __attribute__((ext_vector_type(4)));

// workspace layout (bytes):
//   [0,      65536)   per-image histograms, 64*256 u32
//   [65536,  81920)   packed LUTs, 64 images * 64 u32 words (4 u8 entries/word)
//   [81920,  86016)   accumulator slots, NSLOT * 2 u64
//   [131072, +64MB)   optional u8 image (fast path, if ws_size permits)
#define WS_HIST 0
#define WS_LUTP 65536
#define WS_ACC  81920
#define WS_SMALL 86016
#define WS_U8   (128 * 1024)
#define WS_FAST (WS_U8 + (size_t)NIMG * NPIX)

__device__ __forceinline__ int lut_gather(unsigned int lutw, int v) {
    // LUT distributed across the wave: lane i holds packed bytes lut[4i..4i+3].
    // ds_bpermute is a conflict-free crossbar (no bank serialization).
    unsigned int w = (unsigned int)__builtin_amdgcn_ds_bpermute(v & 0xFC, (int)lutw);
    return (int)((w >> ((v & 3) << 3)) & 0xFFu);
}

template <bool WRITE_U8>
__global__ __launch_bounds__(256) void hist_kernel(const float* __restrict__ img,
                                                   unsigned int* __restrict__ ghist,
                                                   unsigned char* __restrict__ u8img) {
    __shared__ unsigned int lh[NBINS];
    const int b = blockIdx.y;
    lh[threadIdx.x] = 0u;
    __syncthreads();
    const size_t base = (size_t)b * NPIX;
    const f32x4* p = (const f32x4*)(img + base);
    uchar4* q8 = (uchar4*)(u8img + base);
    const int nvec = NPIX / 4;
    const int stride = gridDim.x * 256;
    for (int i = blockIdx.x * 256 + threadIdx.x; i < nvec; i += stride) {
        f32x4 v = WRITE_U8 ? __builtin_nontemporal_load(&p[i]) : p[i];
        int i0 = min(max((int)v[0], 0), 255);
        int i1 = min(max((int)v[1], 0), 255);
        int i2 = min(max((int)v[2], 0), 255);
        int i3 = min(max((int)v[3], 0), 255);
        atomicAdd(&lh[i0], 1u);
        atomicAdd(&lh[i1], 1u);
        atomicAdd(&lh[i2], 1u);
        atomicAdd(&lh[i3], 1u);
        if (WRITE_U8) {
            q8[i] = make_uchar4((unsigned char)i0, (unsigned char)i1,
                                (unsigned char)i2, (unsigned char)i3);
        }
    }
    __syncthreads();
    unsigned int c = lh[threadIdx.x];
    if (c) atomicAdd(&ghist[b * NBINS + threadIdx.x], c);
}

__global__ __launch_bounds__(256) void lut_kernel(const unsigned int* __restrict__ ghist,
                                                  unsigned int* __restrict__ lutp) {
    __shared__ float cdf[NBINS];
    __shared__ unsigned char lut8[NBINS];
    __shared__ float s_min;
    const int b = blockIdx.x;
    const int t = threadIdx.x;
    cdf[t] = (float)ghist[b * NBINS + t];
    __syncthreads();
    for (int off = 1; off < NBINS; off <<= 1) {
        float add = (t >= off) ? cdf[t - off] : 0.0f;
        __syncthreads();
        cdf[t] += add;
        __syncthreads();
    }
    if (t == 0) {
        float m = 0.0f;
        for (int i = 0; i < NBINS; ++i) {
            if (cdf[i] > 0.0f) { m = cdf[i]; break; }
        }
        s_min = m;
    }
    __syncthreads();
    const float scale = 255.0f / fmaxf((float)NPIX - s_min, 1.0f);
    float L = fminf(fmaxf(rintf((cdf[t] - s_min) * scale), 0.0f), 255.0f);
    lut8[t] = (unsigned char)L;
    __syncthreads();
    if (t < 64) {
        unsigned int w = (unsigned int)lut8[4 * t] |
                         ((unsigned int)lut8[4 * t + 1] << 8) |
                         ((unsigned int)lut8[4 * t + 2] << 16) |
                         ((unsigned int)lut8[4 * t + 3] << 24);
        lutp[b * 64 + t] = w;
    }
}

template <bool USE_U8>
__global__ __launch_bounds__(256) void lap_kernel(const float* __restrict__ img,
                                                  const unsigned char* __restrict__ u8img,
                                                  const unsigned int* __restrict__ lutp,
                                                  unsigned long long* __restrict__ acc) {
    __shared__ unsigned short eqS[RSTRIP + 2][W];   // 36 KB
    const int b = blockIdx.y;
    const int y0 = blockIdx.x * RSTRIP;
    const int t = threadIdx.x;
    const int x0 = t * 4;
    const unsigned int lutw = lutp[b * 64 + (t & 63)];
    const size_t base = (size_t)b * NPIX;

    // stage RSTRIP+2 eq rows (halo top/bottom; OOB rows are zero = conv zero-pad of eq)
    for (int r = 0; r < RSTRIP + 2; ++r) {
        const int gy = y0 - 1 + r;
        ushort4 e = make_ushort4(0, 0, 0, 0);
        if (gy >= 0 && gy < H) {
            int v0, v1, v2, v3;
            if (USE_U8) {
                uchar4 c = *(const uchar4*)(u8img + base + (size_t)gy * W + x0);
                v0 = c.x; v1 = c.y; v2 = c.z; v3 = c.w;
            } else {
                f32x4 c = *(const f32x4*)(img + base + (size_t)gy * W + x0);
                v0 = min(max((int)c[0], 0), 255);
                v1 = min(max((int)c[1], 0), 255);
                v2 = min(max((int)c[2], 0), 255);
                v3 = min(max((int)c[3], 0), 255);
            }
            e.x = (unsigned short)lut_gather(lutw, v0);
            e.y = (unsigned short)lut_gather(lutw, v1);
            e.z = (unsigned short)lut_gather(lutw, v2);
            e.w = (unsigned short)lut_gather(lutw, v3);
        }
        *(ushort4*)&eqS[r][x0] = e;
    }
    __syncthreads();

    int s = 0;
    int q = 0;   // per-thread max 16*4*1020^2 = 6.7e7 < 2^31
    for (int r = 1; r <= RSTRIP; ++r) {
        ushort4 c = *(const ushort4*)&eqS[r][x0];
        ushort4 u = *(const ushort4*)&eqS[r - 1][x0];
        ushort4 d = *(const ushort4*)&eqS[r + 1][x0];
        const int el = (x0 > 0) ? (int)eqS[r][x0 - 1] : 0;
        const int er = (x0 + 4 < W) ? (int)eqS[r][x0 + 4] : 0;
        const int c0 = c.x, c1 = c.y, c2 = c.z, c3 = c.w;
        const int l0 = (int)u.x + (int)d.x + el + c1 - 4 * c0;
        const int l1 = (int)u.y + (int)d.y + c0 + c2 - 4 * c1;
        const int l2 = (int)u.z + (int)d.z + c1 + c3 - 4 * c2;
        const int l3 = (int)u.w + (int)d.w + c2 + er - 4 * c3;
        s += l0 + l1 + l2 + l3;
        q += __mul24(l0, l0) + __mul24(l1, l1) + __mul24(l2, l2) + __mul24(l3, l3);
    }

    long long S = s, Q = q;
    for (int off = 32; off > 0; off >>= 1) {
        S += __shfl_down(S, off, 64);
        Q += __shfl_down(Q, off, 64);
    }
    __shared__ long long ss[4], sq[4];
    const int wave = t >> 6, lane = t & 63;
    if (lane == 0) { ss[wave] = S; sq[wave] = Q; }
    __syncthreads();
    if (t == 0) {
        long long St = ss[0] + ss[1] + ss[2] + ss[3];
        long long Qt = sq[0] + sq[1] + sq[2] + sq[3];
        const int slot = (blockIdx.x + blockIdx.y * gridDim.x) & (NSLOT - 1);
        atomicAdd(&acc[2 * slot], (unsigned long long)St);
        atomicAdd(&acc[2 * slot + 1], (unsigned long long)Qt);
    }
}

__global__ __launch_bounds__(256) void finalize_kernel(const unsigned long long* __restrict__ acc,
                                                       float* __restrict__ out) {
    const int t = threadIdx.x;
    long long S = (long long)acc[2 * t];
    long long Q = (long long)acc[2 * t + 1];
    for (int off = 32; off > 0; off >>= 1) {
        S += __shfl_down(S, off, 64);
        Q += __shfl_down(Q, off, 64);
    }
    __shared__ long long ss[4], sq[4];
    const int wave = t >> 6, lane = t & 63;
    if (lane == 0) { ss[wave] = S; sq[wave] = Q; }
    __syncthreads();
    if (t == 0) {
        long long St = ss[0] + ss[1] + ss[2] + ss[3];
        long long Qt = sq[0] + sq[1] + sq[2] + sq[3];
        // lap = lap_int / 255 exactly; var = (Q/255^2 - (S/255)^2/N) / (N-1)
        const double N = (double)NTOT;
        double Sr = (double)St / 255.0;
        double Qr = (double)Qt / 65025.0;
        out[0] = (float)((Qr - Sr * Sr / N) / (N - 1.0));
    }
}

extern "C" void kernel_launch(void* const* d_in, const int* in_sizes, int n_in,
                              void* d_out, int out_size, void* d_ws, size_t ws_size,
                              hipStream_t stream) {
    const float* img = (const float*)d_in[0];
    float* out = (float*)d_out;

    unsigned int* ghist       = (unsigned int*)((char*)d_ws + WS_HIST);
    unsigned int* lutp        = (unsigned int*)((char*)d_ws + WS_LUTP);
    unsigned long long* acc   = (unsigned long long*)((char*)d_ws + WS_ACC);
    unsigned char* u8img      = (unsigned char*)((char*)d_ws + WS_U8);

    const bool fast = (ws_size >= WS_FAST);

    hipMemsetAsync(d_ws, 0, WS_SMALL, stream);

    dim3 hgrid(64, NIMG);
    if (fast) hist_kernel<true><<<hgrid, 256, 0, stream>>>(img, ghist, u8img);
    else      hist_kernel<false><<<hgrid, 256, 0, stream>>>(img, ghist, u8img);

    lut_kernel<<<NIMG, NBINS, 0, stream>>>(ghist, lutp);

    dim3 lgrid(H / RSTRIP, NIMG);
    if (fast) lap_kernel<true><<<lgrid, 256, 0, stream>>>(img, u8img, lutp, acc);
    else      lap_kernel<false><<<lgrid, 256, 0, stream>>>(img, u8img, lutp, acc);

    finalize_kernel<<<1, 256, 0, stream>>>(acc, out);
}

// Round 3
// 127.095 us; speedup vs baseline: 1.6659x; 1.0772x over previous
//
#include <hip/hip_runtime.h>

#define W 1024
#define H 1024
#define NIMG 64
#define NBINS 256
#define NPIX (W * H)                       // per image
#define NTOT ((long long)NIMG * NPIX)      // 67108864
#define NSLOT 256
#define RPW 8                              // rows per wave (lap)

typedef float f32x4 __attribute__((ext_vector_type(4)));

// workspace layout (bytes):
//   [0,      65536)   per-image histograms, 64*256 u32
//   [65536,  81920)   packed LUTs, 64 images * 64 u32 words (4 u8 entries/word)
//   [81920,  86016)   accumulator slots, NSLOT * 2 u64
//   [131072, +64MB)   u8 image (fast path, if ws_size permits)
#define WS_HIST 0
#define WS_LUTP 65536
#define WS_ACC  81920
#define WS_SMALL 86016
#define WS_U8   (128 * 1024)
#define WS_FAST (WS_U8 + (size_t)NIMG * NPIX)

template <bool WRITE_U8>
__global__ __launch_bounds__(256) void hist_kernel(const float* __restrict__ img,
                                                   unsigned int* __restrict__ ghist,
                                                   unsigned char* __restrict__ u8img) {
    __shared__ unsigned int lh[NBINS];
    const int b = blockIdx.y;
    lh[threadIdx.x] = 0u;
    __syncthreads();
    const size_t base = (size_t)b * NPIX;
    const f32x4* p = (const f32x4*)(img + base);
    uchar4* q8 = (uchar4*)(u8img + base);
    const int nvec = NPIX / 4;
    const int stride = gridDim.x * 256;
    for (int i = blockIdx.x * 256 + threadIdx.x; i < nvec; i += stride) {
        f32x4 v = __builtin_nontemporal_load(&p[i]);
        int i0 = min(max((int)v[0], 0), 255);
        int i1 = min(max((int)v[1], 0), 255);
        int i2 = min(max((int)v[2], 0), 255);
        int i3 = min(max((int)v[3], 0), 255);
        atomicAdd(&lh[i0], 1u);
        atomicAdd(&lh[i1], 1u);
        atomicAdd(&lh[i2], 1u);
        atomicAdd(&lh[i3], 1u);
        if (WRITE_U8) {
            q8[i] = make_uchar4((unsigned char)i0, (unsigned char)i1,
                                (unsigned char)i2, (unsigned char)i3);
        }
    }
    __syncthreads();
    unsigned int c = lh[threadIdx.x];
    if (c) atomicAdd(&ghist[b * NBINS + threadIdx.x], c);
}

__global__ __launch_bounds__(256) void lut_kernel(const unsigned int* __restrict__ ghist,
                                                  unsigned int* __restrict__ lutp) {
    __shared__ float cdf[NBINS];
    __shared__ unsigned char lut8[NBINS];
    __shared__ float s_min;
    const int b = blockIdx.x;
    const int t = threadIdx.x;
    cdf[t] = (float)ghist[b * NBINS + t];
    __syncthreads();
    for (int off = 1; off < NBINS; off <<= 1) {
        float add = (t >= off) ? cdf[t - off] : 0.0f;
        __syncthreads();
        cdf[t] += add;
        __syncthreads();
    }
    if (t == 0) {
        float m = 0.0f;
        for (int i = 0; i < NBINS; ++i) {
            if (cdf[i] > 0.0f) { m = cdf[i]; break; }
        }
        s_min = m;
    }
    __syncthreads();
    const float scale = 255.0f / fmaxf((float)NPIX - s_min, 1.0f);
    float L = fminf(fmaxf(rintf((cdf[t] - s_min) * scale), 0.0f), 255.0f);
    lut8[t] = (unsigned char)L;
    __syncthreads();
    if (t < 64) {
        unsigned int w = (unsigned int)lut8[4 * t] |
                         ((unsigned int)lut8[4 * t + 1] << 8) |
                         ((unsigned int)lut8[4 * t + 2] << 16) |
                         ((unsigned int)lut8[4 * t + 3] << 24);
        lutp[b * 64 + t] = w;
    }
}

// lap: one wave per RPW-row strip; lane owns 16 consecutive px; eq rows held as
// 4 packed-u8 u32 registers; up/down from register pipeline; left/right via shfl.
// No LDS staging (bpermute needs no LDS allocation).
template <bool USE_U8>
__global__ __launch_bounds__(256) void lap_kernel(const float* __restrict__ img,
                                                  const unsigned char* __restrict__ u8img,
                                                  const unsigned int* __restrict__ lutp,
                                                  unsigned long long* __restrict__ acc) {
    const int b = blockIdx.y;
    const int lane = threadIdx.x & 63;
    const int wv = threadIdx.x >> 6;
    const int y0 = blockIdx.x * (RPW * 4) + wv * RPW;
    const int col0 = lane * 16;
    const unsigned int lutw = lutp[b * 64 + lane];
    const size_t base = (size_t)b * NPIX;
    const unsigned char* rowp8 = u8img + base + col0;
    const float* rowpf = img + base + col0;

    unsigned int p_[4], c_[4], n_[4];

    auto load_raw = [&](int gy, unsigned int raw[4]) {
        if ((unsigned)gy < (unsigned)H) {
            if (USE_U8) {
                uint4 r = *(const uint4*)(rowp8 + (size_t)gy * W);
                raw[0] = r.x; raw[1] = r.y; raw[2] = r.z; raw[3] = r.w;
            } else {
                const f32x4* fp = (const f32x4*)(rowpf + (size_t)gy * W);
#pragma unroll
                for (int k = 0; k < 4; ++k) {
                    f32x4 v = fp[k];
                    unsigned int w = (unsigned int)min(max((int)v[0], 0), 255);
                    w |= (unsigned int)min(max((int)v[1], 0), 255) << 8;
                    w |= (unsigned int)min(max((int)v[2], 0), 255) << 16;
                    w |= (unsigned int)min(max((int)v[3], 0), 255) << 24;
                    raw[k] = w;
                }
            }
        } else {
            raw[0] = raw[1] = raw[2] = raw[3] = 0u;
        }
    };
    auto gather_row = [&](const unsigned int raw[4], bool valid, unsigned int ew[4]) {
#pragma unroll
        for (int k = 0; k < 4; ++k) {
            unsigned int out = 0u;
#pragma unroll
            for (int j = 0; j < 4; ++j) {
                int v = (int)((raw[k] >> (8 * j)) & 0xFFu);
                unsigned int e = (unsigned int)__builtin_amdgcn_ds_bpermute(v & 0xFC, (int)lutw);
                out |= ((e >> ((v & 3) << 3)) & 0xFFu) << (8 * j);
            }
            ew[k] = valid ? out : 0u;
        }
    };

    unsigned int rawB[4], rawC[4];
    load_raw(y0 - 1, rawB);
    gather_row(rawB, y0 - 1 >= 0, p_);
    load_raw(y0, rawB);
    gather_row(rawB, true, c_);
    load_raw(y0 + 1, rawB);   // raw of next row, gathered at loop top

    int s = 0, q = 0;   // q max: 8*16*1020^2 = 1.33e8 < 2^31
#pragma unroll
    for (int rr = 0; rr < RPW; ++rr) {
        const int gy = y0 + rr;
        if (rr + 1 < RPW) load_raw(gy + 2, rawC);     // prefetch one row ahead
        gather_row(rawB, gy + 1 < H, n_);

        unsigned int t3 = (unsigned int)__shfl_up((int)c_[3], 1, 64);
        const int lw = (lane == 0) ? 0 : (int)(t3 >> 24);
        unsigned int t0 = (unsigned int)__shfl_down((int)c_[0], 1, 64);
        const int rw = (lane == 63) ? 0 : (int)(t0 & 0xFFu);

#pragma unroll
        for (int p = 0; p < 16; ++p) {
            const int k = p >> 2, sh = (p & 3) << 3;
            const int c = (int)((c_[k] >> sh) & 0xFFu);
            const int u = (int)((p_[k] >> sh) & 0xFFu);
            const int d = (int)((n_[k] >> sh) & 0xFFu);
            const int l = (p == 0) ? lw
                        : (int)((c_[(p - 1) >> 2] >> (((p - 1) & 3) << 3)) & 0xFFu);
            const int r = (p == 15) ? rw
                        : (int)((c_[(p + 1) >> 2] >> (((p + 1) & 3) << 3)) & 0xFFu);
            const int lap = u + d + l + r - 4 * c;
            s += lap;
            q += lap * lap;
        }
#pragma unroll
        for (int k = 0; k < 4; ++k) { p_[k] = c_[k]; c_[k] = n_[k]; rawB[k] = rawC[k]; }
    }

    long long S = s, Q = q;
    for (int off = 32; off > 0; off >>= 1) {
        S += __shfl_down(S, off, 64);
        Q += __shfl_down(Q, off, 64);
    }
    if (lane == 0) {
        const int wid = (blockIdx.x + blockIdx.y * gridDim.x) * 4 + wv;
        const int slot = wid & (NSLOT - 1);
        atomicAdd(&acc[2 * slot], (unsigned long long)S);
        atomicAdd(&acc[2 * slot + 1], (unsigned long long)Q);
    }
}

__global__ __launch_bounds__(256) void finalize_kernel(const unsigned long long* __restrict__ acc,
                                                       float* __restrict__ out) {
    const int t = threadIdx.x;
    long long S = (long long)acc[2 * t];
    long long Q = (long long)acc[2 * t + 1];
    for (int off = 32; off > 0; off >>= 1) {
        S += __shfl_down(S, off, 64);
        Q += __shfl_down(Q, off, 64);
    }
    __shared__ long long ss[4], sq[4];
    const int wave = t >> 6, lane = t & 63;
    if (lane == 0) { ss[wave] = S; sq[wave] = Q; }
    __syncthreads();
    if (t == 0) {
        long long St = ss[0] + ss[1] + ss[2] + ss[3];
        long long Qt = sq[0] + sq[1] + sq[2] + sq[3];
        // lap = lap_int / 255 exactly; var = (Q/255^2 - (S/255)^2/N) / (N-1)
        const double N = (double)NTOT;
        double Sr = (double)St / 255.0;
        double Qr = (double)Qt / 65025.0;
        out[0] = (float)((Qr - Sr * Sr / N) / (N - 1.0));
    }
}

extern "C" void kernel_launch(void* const* d_in, const int* in_sizes, int n_in,
                              void* d_out, int out_size, void* d_ws, size_t ws_size,
                              hipStream_t stream) {
    const float* img = (const float*)d_in[0];
    float* out = (float*)d_out;

    unsigned int* ghist     = (unsigned int*)((char*)d_ws + WS_HIST);
    unsigned int* lutp      = (unsigned int*)((char*)d_ws + WS_LUTP);
    unsigned long long* acc = (unsigned long long*)((char*)d_ws + WS_ACC);
    unsigned char* u8img    = (unsigned char*)((char*)d_ws + WS_U8);

    const bool fast = (ws_size >= WS_FAST);

    hipMemsetAsync(d_ws, 0, WS_SMALL, stream);

    dim3 hgrid(64, NIMG);
    if (fast) hist_kernel<true><<<hgrid, 256, 0, stream>>>(img, ghist, u8img);
    else      hist_kernel<false><<<hgrid, 256, 0, stream>>>(img, ghist, u8img);

    lut_kernel<<<NIMG, NBINS, 0, stream>>>(ghist, lutp);

    dim3 lgrid(H / (RPW * 4), NIMG);
    if (fast) lap_kernel<true><<<lgrid, 256, 0, stream>>>(img, u8img, lutp, acc);
    else      lap_kernel<false><<<lgrid, 256, 0, stream>>>(img, u8img, lutp, acc);

    finalize_kernel<<<1, 256, 0, stream>>>(acc, out);
}